// Round 4
// baseline (1232.868 us; speedup 1.0000x reference)
//
#include <hip/hip_runtime.h>
#include <math.h>

// ---------------------------------------------------------------------------
// UKF(2048) == linear Kalman update (affine model => sigma machinery collapses):
//   xp = A x + B u + c1 ; Pk = P + Q
//   T = C Pk ; Py = T C^T + R ; G = T^T (= Pxy)
//   X ~= Py^{-1} via Newton-Schulz: X1 = a(2I - a Py) analytic (free),
//     3 bf16-hi GEMM iters, 1 exact-split iter
//   P_out = Pk - (G X) G^T ; z = Py^{-1} r via X-precond refinement (matvecs)
//   x_out = xp + G z
// GEMM: split-bf16 MFMA TN ( TN(A,B)[m][n] = sum_k A[m][k]*B[n][k] ),
// 128x128 tile, 8 waves, BK=64, XOR-swizzled LDS (pre-swizzled global src),
// double-buffered 2-phase pipeline (prefetch next tile before compute),
// XCD-aware block swizzle.
// ---------------------------------------------------------------------------

typedef unsigned short u16;
typedef unsigned int u32;
typedef __attribute__((ext_vector_type(8))) short bf16x8;
typedef __attribute__((ext_vector_type(4))) float f32x4;

#define GN 2048
#define NNE ((size_t)GN * (size_t)GN)

__device__ __forceinline__ u16 f2bf(float f) {
    union { float f; u32 u; } x; x.f = f;
    u32 r = x.u + 0x7fffu + ((x.u >> 16) & 1u);   // RNE
    return (u16)(r >> 16);
}
__device__ __forceinline__ float bf2f(u16 b) {
    union { u32 u; float f; } x; x.u = ((u32)b) << 16;
    return x.f;
}

__device__ __forceinline__ void gload16(const u16* g, u16* l) {
    __builtin_amdgcn_global_load_lds((const __attribute__((address_space(1))) u32*)g,
                                     (__attribute__((address_space(3))) u32*)l, 16, 0, 0);
}

// ---------------- elementwise / conversion ----------------

__global__ void fuse_pk(const float* __restrict__ P, const float* __restrict__ Q,
                        float* __restrict__ Pf, u16* __restrict__ Ph, u16* __restrict__ Pl)
{
    size_t i = (size_t)blockIdx.x * 256 + threadIdx.x;   // over NNE/4
    float4 p = ((const float4*)P)[i];
    float4 q = ((const float4*)Q)[i];
    float s[4] = {p.x + q.x, p.y + q.y, p.z + q.z, p.w + q.w};
    ((float4*)Pf)[i] = make_float4(s[0], s[1], s[2], s[3]);
    ushort4 h, l;
    u16* hp = (u16*)&h; u16* lp = (u16*)&l;
#pragma unroll
    for (int e = 0; e < 4; ++e) {
        u16 hb = f2bf(s[e]);
        hp[e] = hb;
        lp[e] = f2bf(s[e] - bf2f(hb));
    }
    ((ushort4*)Ph)[i] = h;
    ((ushort4*)Pl)[i] = l;
}

__global__ void conv_hl(const float* __restrict__ S, u16* __restrict__ H, u16* __restrict__ L)
{
    size_t i = (size_t)blockIdx.x * 256 + threadIdx.x;   // over NNE/4
    float4 p = ((const float4*)S)[i];
    float s[4] = {p.x, p.y, p.z, p.w};
    ushort4 h, l;
    u16* hp = (u16*)&h; u16* lp = (u16*)&l;
#pragma unroll
    for (int e = 0; e < 4; ++e) {
        u16 hb = f2bf(s[e]);
        hp[e] = hb;
        lp[e] = f2bf(s[e] - bf2f(hb));
    }
    ((ushort4*)H)[i] = h;
    ((ushort4*)L)[i] = l;
}

__global__ void transpose_pair(const u16* __restrict__ Sh, const u16* __restrict__ Sl,
                               u16* __restrict__ Dh, u16* __restrict__ Dl)
{
    __shared__ u16 th[32][33];
    __shared__ u16 tl[32][33];
    int bi = blockIdx.y * 32, bj = blockIdx.x * 32;
    int r = threadIdx.x >> 5, c = threadIdx.x & 31;
    for (int rr = r; rr < 32; rr += 8) {
        th[rr][c] = Sh[(size_t)(bi + rr) * GN + bj + c];
        tl[rr][c] = Sl[(size_t)(bi + rr) * GN + bj + c];
    }
    __syncthreads();
    for (int rr = r; rr < 32; rr += 8) {
        Dh[(size_t)(bj + rr) * GN + bi + c] = th[c][rr];
        Dl[(size_t)(bj + rr) * GN + bi + c] = tl[c][rr];
    }
}

// X1 = a*(2I - a*Py) : first Newton-Schulz step is elementwise for X0 = a*I
__global__ void ns_init(const u16* __restrict__ Pyh, const u16* __restrict__ Pyl,
                        const float* __restrict__ alphap, u16* __restrict__ X)
{
    float a = alphap[0];
    size_t i4 = (size_t)blockIdx.x * 256 + threadIdx.x;   // over NNE/4
    size_t base = i4 * 4;
    u32 row = (u32)(base >> 11);            // /GN
    u32 col0 = (u32)(base & (GN - 1));      // %GN  (4 elems stay in-row)
    ushort4 h = ((const ushort4*)Pyh)[i4];
    ushort4 lo = ((const ushort4*)Pyl)[i4];
    u16 hv[4] = {h.x, h.y, h.z, h.w};
    u16 lv[4] = {lo.x, lo.y, lo.z, lo.w};
    ushort4 o;
    u16* op = (u16*)&o;
#pragma unroll
    for (int e = 0; e < 4; ++e) {
        float py = bf2f(hv[e]) + bf2f(lv[e]);
        float v = a * (((row == col0 + e) ? 2.0f : 0.0f) - a * py);
        op[e] = f2bf(v);
    }
    ((ushort4*)X)[i4] = o;
}

// ---------------- vector kernels ----------------

__global__ void matvec_f32(const float* __restrict__ A, const float* __restrict__ v,
                           const float* __restrict__ addv, float* __restrict__ out, int n)
{
    int wid = threadIdx.x >> 6, lane = threadIdx.x & 63;
    int row = blockIdx.x * 4 + wid;
    if (row >= n) return;
    const float* arow = A + (size_t)row * n;
    float s = 0.f;
    for (int j = lane; j < n; j += 64) s += arow[j] * v[j];
#pragma unroll
    for (int off = 32; off > 0; off >>= 1) s += __shfl_down(s, off);
    if (lane == 0) out[row] = s + (addv ? addv[row] : 0.f);
}

// out[row] = (addv ? addv[row] : 0) + sign * dot((hi+lo)[row,:], v)
__global__ void matvec_hl(const u16* __restrict__ Mh, const u16* __restrict__ Ml,
                          const float* __restrict__ v, const float* __restrict__ addv,
                          float* __restrict__ out, float sign, int n)
{
    int wid = threadIdx.x >> 6, lane = threadIdx.x & 63;
    int row = blockIdx.x * 4 + wid;
    if (row >= n) return;
    const u16* hr = Mh + (size_t)row * n;
    const u16* lr = Ml ? Ml + (size_t)row * n : (const u16*)0;
    float s = 0.f;
    for (int j = lane * 8; j < n; j += 512) {
        uint4 hb = *(const uint4*)&hr[j];
        float4 v0 = *(const float4*)&v[j];
        float4 v1 = *(const float4*)&v[j + 4];
        u32 hw[4] = {hb.x, hb.y, hb.z, hb.w};
        float m[8];
#pragma unroll
        for (int e = 0; e < 4; ++e) {
            m[2 * e]     = bf2f((u16)(hw[e] & 0xffffu));
            m[2 * e + 1] = bf2f((u16)(hw[e] >> 16));
        }
        if (lr) {
            uint4 lb = *(const uint4*)&lr[j];
            u32 lw[4] = {lb.x, lb.y, lb.z, lb.w};
#pragma unroll
            for (int e = 0; e < 4; ++e) {
                m[2 * e]     += bf2f((u16)(lw[e] & 0xffffu));
                m[2 * e + 1] += bf2f((u16)(lw[e] >> 16));
            }
        }
        s += m[0] * v0.x + m[1] * v0.y + m[2] * v0.z + m[3] * v0.w
           + m[4] * v1.x + m[5] * v1.y + m[6] * v1.z + m[7] * v1.w;
    }
#pragma unroll
    for (int off = 32; off > 0; off >>= 1) s += __shfl_down(s, off);
    if (lane == 0) out[row] = (addv ? addv[row] : 0.f) + sign * s;
}

__global__ void vec_sub(const float* __restrict__ a, const float* __restrict__ b,
                        float* __restrict__ o, int n)
{
    int i = blockIdx.x * 256 + threadIdx.x;
    if (i < n) o[i] = a[i] - b[i];
}

__global__ void vec_fill(float* __restrict__ o, float val, int n)
{
    int i = blockIdx.x * 256 + threadIdx.x;
    if (i < n) o[i] = val;
}

__global__ void normsq(const float* __restrict__ v, float* __restrict__ out, int n)
{
    __shared__ float sm[256];
    float s = 0.f;
    for (int i = threadIdx.x; i < n; i += 256) { float x = v[i]; s += x * x; }
    sm[threadIdx.x] = s;
    __syncthreads();
    for (int w = 128; w > 0; w >>= 1) {
        if (threadIdx.x < w) sm[threadIdx.x] += sm[threadIdx.x + w];
        __syncthreads();
    }
    if (threadIdx.x == 0) out[0] = sm[0];
}

__global__ void alpha_k(const float* __restrict__ ns9, const float* __restrict__ ns10,
                        float* __restrict__ alpha)
{
    float lam = sqrtf(ns10[0] / ns9[0]);
    alpha[0] = 2.0f / (1.3f * lam);
}

// ---------------- MFMA TN-GEMM: 128x128, 8 waves, BK=64, dbuf 2-phase ----------------
// O = op(MODE){ sum_s A_s * B_s^T } ; MODE 0: S ; 1: S+Dm ; 2: Dm-S ; 3: 2I-S
template <int MODE, int WHI, int WLO, int WF32>
__global__ __launch_bounds__(512, 2) void mfma_gemm(
    const u16* A0, const u16* B0, const u16* A1, const u16* B1,
    const u16* A2, const u16* B2, int nseg,
    const float* Dm, float* Of, u16* Ohi, u16* Olo)
{
    __shared__ __align__(16) u16 As0[128 * 64];
    __shared__ __align__(16) u16 Bs0[128 * 64];
    __shared__ __align__(16) u16 As1[128 * 64];
    __shared__ __align__(16) u16 Bs1[128 * 64];
    const int t = threadIdx.x;
    const int wid = t >> 6, l = t & 63;
    const int wr = wid >> 2, wc = wid & 3;            // 2x4 waves, tile 64x32

    // XCD-aware block swizzle: 256 blocks (16x16), 8 XCDs, bijective
    const int lin = blockIdx.y * 16 + blockIdx.x;
    const int swz = (lin & 7) * 32 + (lin >> 3);
    const int m0 = (swz >> 4) * 128, n0 = (swz & 15) * 128;

    f32x4 acc[4][2] = {};

    // staging: wave w rows [w*16, w*16+16), 2 gloads of 8 rows each.
    // LDS linear; swizzle via permuted GLOBAL source column (rule #21):
    // phys slot content(row, sl) = global col sl^(row&7); row&7 == l>>3.
    const int srow = l >> 3;                            // 0..7
    const int scol = (((l & 7) ^ srow) << 3);           // source col (elems)
    const size_t ago = (size_t)(m0 + wid * 16 + srow) * GN + scol;
    const size_t bgo = (size_t)(n0 + wid * 16 + srow) * GN + scol;
    const int ldsW = wid * 1024;

    // read side: logical k-slot (ks*4 + l>>4) XOR (row&7)
    const int lrow = l & 15;
    const int lq = l >> 4;
    const int lb = l & 7;
    int aoff[4][2], boff[2][2];
#pragma unroll
    for (int mi = 0; mi < 4; ++mi) {
        int r = wr * 64 + mi * 16 + lrow;
#pragma unroll
        for (int ks = 0; ks < 2; ++ks)
            aoff[mi][ks] = r * 64 + (((ks * 4 + lq) ^ lb) << 3);
    }
#pragma unroll
    for (int ni = 0; ni < 2; ++ni) {
        int r = wc * 32 + ni * 16 + lrow;
#pragma unroll
        for (int ks = 0; ks < 2; ++ks)
            boff[ni][ks] = r * 64 + (((ks * 4 + lq) ^ lb) << 3);
    }

    const int nt = nseg * 32;   // BK=64 -> 32 tiles per segment; nt is even

    auto stage = [&](int tile, u16* Ad, u16* Bd) {
        int sn = tile >> 5;
        size_t kn = (size_t)(tile & 31) << 6;
        const u16* Ap = (sn == 0) ? A0 : ((sn == 1) ? A1 : A2);
        const u16* Bp = (sn == 0) ? B0 : ((sn == 1) ? B1 : B2);
        const u16* gA = Ap + ago + kn;
        const u16* gB = Bp + bgo + kn;
        gload16(gA, Ad + ldsW);
        gload16(gA + (size_t)8 * GN, Ad + ldsW + 512);
        gload16(gB, Bd + ldsW);
        gload16(gB + (size_t)8 * GN, Bd + ldsW + 512);
    };
    auto compute = [&](const u16* Asrc, const u16* Bsrc) {
#pragma unroll
        for (int ks = 0; ks < 2; ++ks) {
            bf16x8 af[4], bq[2];
#pragma unroll
            for (int mi = 0; mi < 4; ++mi)
                af[mi] = *(const bf16x8*)&Asrc[aoff[mi][ks]];
#pragma unroll
            for (int ni = 0; ni < 2; ++ni)
                bq[ni] = *(const bf16x8*)&Bsrc[boff[ni][ks]];
#pragma unroll
            for (int mi = 0; mi < 4; ++mi)
#pragma unroll
                for (int ni = 0; ni < 2; ++ni)
                    acc[mi][ni] = __builtin_amdgcn_mfma_f32_16x16x32_bf16(
                        af[mi], bq[ni], acc[mi][ni], 0, 0, 0);
        }
    };

    stage(0, As0, Bs0);
    __syncthreads();                       // vmcnt drained -> buf0 ready
    for (int tt = 0; tt < nt; tt += 2) {
        stage(tt + 1, As1, Bs1);           // prefetch while computing buf0
        compute(As0, Bs0);
        __syncthreads();                   // drains own vmcnt -> buf1 ready
        if (tt + 2 < nt) stage(tt + 2, As0, Bs0);
        compute(As1, Bs1);
        __syncthreads();
    }

    // epilogue: C/D frag mapping col = l&15, row = (l>>4)*4 + r
#pragma unroll
    for (int mi = 0; mi < 4; ++mi) {
#pragma unroll
        for (int r = 0; r < 4; ++r) {
            int gm = m0 + wr * 64 + mi * 16 + lq * 4 + r;
            size_t rowo = (size_t)gm * GN;
#pragma unroll
            for (int ni = 0; ni < 2; ++ni) {
                int gn = n0 + wc * 32 + ni * 16 + lrow;
                float v = acc[mi][ni][r];
                if (MODE == 1) v = v + Dm[rowo + gn];
                else if (MODE == 2) v = Dm[rowo + gn] - v;
                else if (MODE == 3) v = ((gm == gn) ? 2.0f : 0.0f) - v;
                if (WF32) Of[rowo + gn] = v;
                if (WHI) {
                    u16 h = f2bf(v);
                    Ohi[rowo + gn] = h;
                    if (WLO) Olo[rowo + gn] = f2bf(v - bf2f(h));
                }
            }
        }
    }
}

// ---------------- host ----------------

extern "C" void kernel_launch(void* const* d_in, const int* in_sizes, int n_in,
                              void* d_out, int out_size, void* d_ws, size_t ws_size,
                              hipStream_t stream)
{
    const int n = GN;
    const float* x  = (const float*)d_in[0];
    const float* y  = (const float*)d_in[1];
    const float* u  = (const float*)d_in[2];
    const float* P  = (const float*)d_in[3];
    const float* Q  = (const float*)d_in[4];
    const float* R  = (const float*)d_in[5];
    const float* A  = (const float*)d_in[6];
    const float* B  = (const float*)d_in[7];
    const float* C  = (const float*)d_in[8];
    const float* D  = (const float*)d_in[9];
    const float* c1 = (const float*)d_in[10];
    const float* c2 = (const float*)d_in[11];

    float* out  = (float*)d_out;
    float* xout = out;          // n
    float* Pf   = out + n;      // n*n fp32: Pk, becomes P_out in place

    // 10 bf16 NxN slots + small fp32 vectors
    u16* wsu = (u16*)d_ws;
    u16* S0 = wsu + 0 * NNE;  // C_hi  -> G_hi
    u16* S1 = wsu + 1 * NNE;  // C_lo  -> G_lo
    u16* S2 = wsu + 2 * NNE;  // Pk_hi -> X odd slots / X5_hi
    u16* S3 = wsu + 3 * NNE;  // Pk_lo -> X5_lo
    u16* S4 = wsu + 4 * NNE;  // T_hi  -> X even slots (X4)
    u16* S5 = wsu + 5 * NNE;  // T_lo
    u16* S6 = wsu + 6 * NNE;  // Py_hi
    u16* S7 = wsu + 7 * NNE;  // Py_lo
    u16* S8 = wsu + 8 * NNE;  // E_hi  -> H_hi
    u16* S9 = wsu + 9 * NNE;  // E_lo  -> H_lo
    float* vecs = (float*)(wsu + 10 * NNE);
    float* t1   = vecs + 0 * n;
    float* xp   = vecs + 1 * n;
    float* ob   = vecs + 2 * n;
    float* ytmp = vecs + 3 * n;
    float* rr   = vecs + 4 * n;
    float* va   = vecs + 5 * n;
    float* vb   = vecs + 6 * n;
    float* z0   = vecs + 7 * n;
    float* z1   = vecs + 8 * n;
    float* rho  = vecs + 9 * n;
    float* scal = vecs + 10 * n;

    dim3 blk256(256), blk512(512);
    dim3 gg(16, 16);

    // Pk = P + Q (fp32 into d_out + hi/lo) ; C -> hi/lo
    fuse_pk<<<4096, blk256, 0, stream>>>(P, Q, Pf, S2, S3);
    conv_hl<<<4096, blk256, 0, stream>>>(C, S0, S1);

    // xp = A x + B u + c1 ; rr = y - (C xp + D u + c2)
    matvec_f32<<<512, blk256, 0, stream>>>(B, u, c1, t1, n);
    matvec_f32<<<512, blk256, 0, stream>>>(A, x, t1, xp, n);
    matvec_f32<<<512, blk256, 0, stream>>>(D, u, c2, ob, n);
    matvec_f32<<<512, blk256, 0, stream>>>(C, xp, ob, ytmp, n);
    vec_sub<<<8, blk256, 0, stream>>>(y, ytmp, rr, n);

    // T = TN(C, Pk) (full split, 3-seg) -> S4/S5
    mfma_gemm<0, 1, 1, 0><<<gg, blk512, 0, stream>>>(S0, S2, S0, S3, S1, S2, 3,
                                                     nullptr, nullptr, S4, S5);
    // Py = TN(T, C) + R (full split, 3-seg) -> S6/S7
    mfma_gemm<1, 1, 1, 0><<<gg, blk512, 0, stream>>>(S4, S0, S4, S1, S5, S0, 3,
                                                     R, nullptr, S6, S7);
    // G = T^T -> S0/S1 (C bf16 dead)
    transpose_pair<<<dim3(64, 64), blk256, 0, stream>>>(S4, S5, S0, S1);

    // power iteration for lambda_max(Py) -> alpha = 2/(1.3*lam)
    vec_fill<<<8, blk256, 0, stream>>>(va, 1.0f, n);
    float* pa = va; float* pb = vb;
    for (int i = 0; i < 9; ++i) {
        matvec_hl<<<512, blk256, 0, stream>>>(S6, nullptr, pa, nullptr, pb, 1.0f, n);
        float* tmp = pa; pa = pb; pb = tmp;
    }
    normsq<<<1, blk256, 0, stream>>>(pa, scal + 0, n);
    matvec_hl<<<512, blk256, 0, stream>>>(S6, nullptr, pa, nullptr, pb, 1.0f, n);
    normsq<<<1, blk256, 0, stream>>>(pb, scal + 1, n);
    alpha_k<<<1, 1, 0, stream>>>(scal + 0, scal + 1, scal + 2);

    // X1 = alpha*(2I - alpha*Py), elementwise (free first NS step) -> S2
    ns_init<<<4096, blk256, 0, stream>>>(S6, S7, scal + 2, S2);

    // 3 cheap NS iterations (hi-only): S2 -> S4 -> S2 -> S4
    u16* ch = S2; u16* oh = S4;
    for (int it = 0; it < 3; ++it) {
        mfma_gemm<3, 1, 0, 0><<<gg, blk512, 0, stream>>>(ch, S6, nullptr, nullptr, nullptr, nullptr, 1,
                                                         nullptr, nullptr, S8, nullptr); // E = 2I - X Py
        mfma_gemm<0, 1, 0, 0><<<gg, blk512, 0, stream>>>(S8, ch, nullptr, nullptr, nullptr, nullptr, 1,
                                                         nullptr, nullptr, oh, nullptr); // Xn = E X
        u16* tmp = ch; ch = oh; oh = tmp;
    }
    // exact-split NS iteration from X4 (== S4, hi-only): X5 -> S2/S3
    mfma_gemm<3, 1, 1, 0><<<gg, blk512, 0, stream>>>(S4, S6, S4, S7, nullptr, nullptr, 2,
                                                     nullptr, nullptr, S8, S9);          // E = 2I - X4*Py(full)
    mfma_gemm<0, 1, 1, 0><<<gg, blk512, 0, stream>>>(S8, S4, S9, S4, nullptr, nullptr, 2,
                                                     nullptr, nullptr, S2, S3);          // X5 = E(full)*X4

    // H = TN(G, X5) (2-seg: Gh*Xh + Gh*Xl) -> S8/S9
    mfma_gemm<0, 1, 1, 0><<<gg, blk512, 0, stream>>>(S0, S2, S0, S3, nullptr, nullptr, 2,
                                                     nullptr, nullptr, S8, S9);
    // P_out = Pk - TN(H, G) (2-seg: Hh*Gh + Hl*Gh) -> Pf in place
    mfma_gemm<2, 0, 0, 1><<<gg, blk512, 0, stream>>>(S8, S0, S9, S0, nullptr, nullptr, 2,
                                                     Pf, Pf, nullptr, nullptr);

    // z = Py^{-1} rr by X-preconditioned iterative refinement (2 steps)
    matvec_hl<<<512, blk256, 0, stream>>>(S2, S3, rr, nullptr, z0, 1.0f, n);   // z0 = X r
    matvec_hl<<<512, blk256, 0, stream>>>(S6, S7, z0, rr, rho, -1.0f, n);      // rho = r - Py z0
    matvec_hl<<<512, blk256, 0, stream>>>(S2, S3, rho, z0, z1, 1.0f, n);       // z1 = z0 + X rho
    matvec_hl<<<512, blk256, 0, stream>>>(S6, S7, z1, rr, rho, -1.0f, n);      // rho = r - Py z1
    matvec_hl<<<512, blk256, 0, stream>>>(S2, S3, rho, z1, z0, 1.0f, n);       // z2 = z1 + X rho
    // x_out = xp + G z2
    matvec_hl<<<512, blk256, 0, stream>>>(S0, S1, z0, xp, xout, 1.0f, n);
}

// Round 5
// 995.095 us; speedup vs baseline: 1.2389x; 1.2389x over previous
//
#include <hip/hip_runtime.h>
#include <math.h>

// ---------------------------------------------------------------------------
// UKF(2048) == linear Kalman update (affine model => sigma machinery collapses):
//   xp = A x + B u + c1 ; Pk = P + Q
//   T = C Pk ; Py = T C^T + R ; G = T^T (= Pxy)
//   X ~= Py^{-1} via Newton-Schulz: X1 = a(2I - a Py) analytic (free),
//     3 bf16-hi GEMM iters, 1 exact-split iter
//   P_out = Pk - (G X) G^T ; z = Py^{-1} r via X-precond refinement (matvecs)
//   x_out = xp + G z
// GEMM: split-bf16 MFMA TN ( TN(A,B)[m][n] = sum_k A[m][k]*B[n][k] ),
// 128x128 tile, 8 waves, BK=64, XOR-swizzled LDS (pre-swizzled global src),
// depth-2 double-buffer with COUNTED s_waitcnt vmcnt(4) + raw s_barrier
// (T3+T4: loads stay in flight across barriers; never drain to 0 mid-loop).
// ---------------------------------------------------------------------------

typedef unsigned short u16;
typedef unsigned int u32;
typedef __attribute__((ext_vector_type(8))) short bf16x8;
typedef __attribute__((ext_vector_type(4))) float f32x4;

#define GN 2048
#define NNE ((size_t)GN * (size_t)GN)

__device__ __forceinline__ u16 f2bf(float f) {
    union { float f; u32 u; } x; x.f = f;
    u32 r = x.u + 0x7fffu + ((x.u >> 16) & 1u);   // RNE
    return (u16)(r >> 16);
}
__device__ __forceinline__ float bf2f(u16 b) {
    union { u32 u; float f; } x; x.u = ((u32)b) << 16;
    return x.f;
}

__device__ __forceinline__ void gload16(const u16* g, u16* l) {
    __builtin_amdgcn_global_load_lds((const __attribute__((address_space(1))) u32*)g,
                                     (__attribute__((address_space(3))) u32*)l, 16, 0, 0);
}

// ---------------- elementwise / conversion ----------------

__global__ void fuse_pk(const float* __restrict__ P, const float* __restrict__ Q,
                        float* __restrict__ Pf, u16* __restrict__ Ph, u16* __restrict__ Pl)
{
    size_t i = (size_t)blockIdx.x * 256 + threadIdx.x;   // over NNE/4
    float4 p = ((const float4*)P)[i];
    float4 q = ((const float4*)Q)[i];
    float s[4] = {p.x + q.x, p.y + q.y, p.z + q.z, p.w + q.w};
    ((float4*)Pf)[i] = make_float4(s[0], s[1], s[2], s[3]);
    ushort4 h, l;
    u16* hp = (u16*)&h; u16* lp = (u16*)&l;
#pragma unroll
    for (int e = 0; e < 4; ++e) {
        u16 hb = f2bf(s[e]);
        hp[e] = hb;
        lp[e] = f2bf(s[e] - bf2f(hb));
    }
    ((ushort4*)Ph)[i] = h;
    ((ushort4*)Pl)[i] = l;
}

__global__ void conv_hl(const float* __restrict__ S, u16* __restrict__ H, u16* __restrict__ L)
{
    size_t i = (size_t)blockIdx.x * 256 + threadIdx.x;   // over NNE/4
    float4 p = ((const float4*)S)[i];
    float s[4] = {p.x, p.y, p.z, p.w};
    ushort4 h, l;
    u16* hp = (u16*)&h; u16* lp = (u16*)&l;
#pragma unroll
    for (int e = 0; e < 4; ++e) {
        u16 hb = f2bf(s[e]);
        hp[e] = hb;
        lp[e] = f2bf(s[e] - bf2f(hb));
    }
    ((ushort4*)H)[i] = h;
    ((ushort4*)L)[i] = l;
}

__global__ void transpose_pair(const u16* __restrict__ Sh, const u16* __restrict__ Sl,
                               u16* __restrict__ Dh, u16* __restrict__ Dl)
{
    __shared__ u16 th[32][33];
    __shared__ u16 tl[32][33];
    int bi = blockIdx.y * 32, bj = blockIdx.x * 32;
    int r = threadIdx.x >> 5, c = threadIdx.x & 31;
    for (int rr = r; rr < 32; rr += 8) {
        th[rr][c] = Sh[(size_t)(bi + rr) * GN + bj + c];
        tl[rr][c] = Sl[(size_t)(bi + rr) * GN + bj + c];
    }
    __syncthreads();
    for (int rr = r; rr < 32; rr += 8) {
        Dh[(size_t)(bj + rr) * GN + bi + c] = th[c][rr];
        Dl[(size_t)(bj + rr) * GN + bi + c] = tl[c][rr];
    }
}

// X1 = a*(2I - a*Py) : first Newton-Schulz step is elementwise for X0 = a*I
__global__ void ns_init(const u16* __restrict__ Pyh, const u16* __restrict__ Pyl,
                        const float* __restrict__ alphap, u16* __restrict__ X)
{
    float a = alphap[0];
    size_t i4 = (size_t)blockIdx.x * 256 + threadIdx.x;   // over NNE/4
    size_t base = i4 * 4;
    u32 row = (u32)(base >> 11);            // /GN
    u32 col0 = (u32)(base & (GN - 1));      // %GN  (4 elems stay in-row)
    ushort4 h = ((const ushort4*)Pyh)[i4];
    ushort4 lo = ((const ushort4*)Pyl)[i4];
    u16 hv[4] = {h.x, h.y, h.z, h.w};
    u16 lv[4] = {lo.x, lo.y, lo.z, lo.w};
    ushort4 o;
    u16* op = (u16*)&o;
#pragma unroll
    for (int e = 0; e < 4; ++e) {
        float py = bf2f(hv[e]) + bf2f(lv[e]);
        float v = a * (((row == col0 + e) ? 2.0f : 0.0f) - a * py);
        op[e] = f2bf(v);
    }
    ((ushort4*)X)[i4] = o;
}

// ---------------- vector kernels ----------------

__global__ void matvec_f32(const float* __restrict__ A, const float* __restrict__ v,
                           const float* __restrict__ addv, float* __restrict__ out, int n)
{
    int wid = threadIdx.x >> 6, lane = threadIdx.x & 63;
    int row = blockIdx.x * 4 + wid;
    if (row >= n) return;
    const float* arow = A + (size_t)row * n;
    float s = 0.f;
    for (int j = lane; j < n; j += 64) s += arow[j] * v[j];
#pragma unroll
    for (int off = 32; off > 0; off >>= 1) s += __shfl_down(s, off);
    if (lane == 0) out[row] = s + (addv ? addv[row] : 0.f);
}

// out[row] = (addv ? addv[row] : 0) + sign * dot((hi+lo)[row,:], v)
__global__ void matvec_hl(const u16* __restrict__ Mh, const u16* __restrict__ Ml,
                          const float* __restrict__ v, const float* __restrict__ addv,
                          float* __restrict__ out, float sign, int n)
{
    int wid = threadIdx.x >> 6, lane = threadIdx.x & 63;
    int row = blockIdx.x * 4 + wid;
    if (row >= n) return;
    const u16* hr = Mh + (size_t)row * n;
    const u16* lr = Ml ? Ml + (size_t)row * n : (const u16*)0;
    float s = 0.f;
    for (int j = lane * 8; j < n; j += 512) {
        uint4 hb = *(const uint4*)&hr[j];
        float4 v0 = *(const float4*)&v[j];
        float4 v1 = *(const float4*)&v[j + 4];
        u32 hw[4] = {hb.x, hb.y, hb.z, hb.w};
        float m[8];
#pragma unroll
        for (int e = 0; e < 4; ++e) {
            m[2 * e]     = bf2f((u16)(hw[e] & 0xffffu));
            m[2 * e + 1] = bf2f((u16)(hw[e] >> 16));
        }
        if (lr) {
            uint4 lb = *(const uint4*)&lr[j];
            u32 lw[4] = {lb.x, lb.y, lb.z, lb.w};
#pragma unroll
            for (int e = 0; e < 4; ++e) {
                m[2 * e]     += bf2f((u16)(lw[e] & 0xffffu));
                m[2 * e + 1] += bf2f((u16)(lw[e] >> 16));
            }
        }
        s += m[0] * v0.x + m[1] * v0.y + m[2] * v0.z + m[3] * v0.w
           + m[4] * v1.x + m[5] * v1.y + m[6] * v1.z + m[7] * v1.w;
    }
#pragma unroll
    for (int off = 32; off > 0; off >>= 1) s += __shfl_down(s, off);
    if (lane == 0) out[row] = (addv ? addv[row] : 0.f) + sign * s;
}

__global__ void vec_sub(const float* __restrict__ a, const float* __restrict__ b,
                        float* __restrict__ o, int n)
{
    int i = blockIdx.x * 256 + threadIdx.x;
    if (i < n) o[i] = a[i] - b[i];
}

__global__ void vec_fill(float* __restrict__ o, float val, int n)
{
    int i = blockIdx.x * 256 + threadIdx.x;
    if (i < n) o[i] = val;
}

__global__ void normsq(const float* __restrict__ v, float* __restrict__ out, int n)
{
    __shared__ float sm[256];
    float s = 0.f;
    for (int i = threadIdx.x; i < n; i += 256) { float x = v[i]; s += x * x; }
    sm[threadIdx.x] = s;
    __syncthreads();
    for (int w = 128; w > 0; w >>= 1) {
        if (threadIdx.x < w) sm[threadIdx.x] += sm[threadIdx.x + w];
        __syncthreads();
    }
    if (threadIdx.x == 0) out[0] = sm[0];
}

__global__ void alpha_k(const float* __restrict__ ns9, const float* __restrict__ ns10,
                        float* __restrict__ alpha)
{
    float lam = sqrtf(ns10[0] / ns9[0]);
    alpha[0] = 2.0f / (1.3f * lam);
}

// ---------------- MFMA TN-GEMM: 128x128, 8 waves, BK=64, counted-vmcnt dbuf --
// O = op(MODE){ sum_s A_s * B_s^T } ; MODE 0: S ; 1: S+Dm ; 2: Dm-S ; 3: 2I-S
template <int MODE, int WHI, int WLO, int WF32>
__global__ __launch_bounds__(512, 2) void mfma_gemm(
    const u16* A0, const u16* B0, const u16* A1, const u16* B1,
    const u16* A2, const u16* B2, int nseg,
    const float* Dm, float* Of, u16* Ohi, u16* Olo)
{
    __shared__ __align__(16) u16 As0[128 * 64];
    __shared__ __align__(16) u16 Bs0[128 * 64];
    __shared__ __align__(16) u16 As1[128 * 64];
    __shared__ __align__(16) u16 Bs1[128 * 64];
    const int t = threadIdx.x;
    const int wid = t >> 6, l = t & 63;
    const int wr = wid >> 2, wc = wid & 3;            // 2x4 waves, tile 64x32
    const int m0 = blockIdx.y * 128, n0 = blockIdx.x * 128;

    f32x4 acc[4][2] = {};

    // staging: wave w rows [w*16, w*16+16), 2 gloads of 8 rows per operand.
    // LDS linear; swizzle via permuted GLOBAL source column (rule #21):
    // phys slot content(row, sl) = global col sl^(row&7); row&7 == l>>3.
    const int srow = l >> 3;                            // 0..7
    const int scol = (((l & 7) ^ srow) << 3);           // source col (elems)
    const size_t ago = (size_t)(m0 + wid * 16 + srow) * GN + scol;
    const size_t bgo = (size_t)(n0 + wid * 16 + srow) * GN + scol;
    const int ldsW = wid * 1024;

    // read side: logical k-slot (ks*4 + l>>4) XOR (row&7)
    const int lrow = l & 15;
    const int lq = l >> 4;
    const int lb = l & 7;
    int aoff[4][2], boff[2][2];
#pragma unroll
    for (int mi = 0; mi < 4; ++mi) {
        int r = wr * 64 + mi * 16 + lrow;
#pragma unroll
        for (int ks = 0; ks < 2; ++ks)
            aoff[mi][ks] = r * 64 + (((ks * 4 + lq) ^ lb) << 3);
    }
#pragma unroll
    for (int ni = 0; ni < 2; ++ni) {
        int r = wc * 32 + ni * 16 + lrow;
#pragma unroll
        for (int ks = 0; ks < 2; ++ks)
            boff[ni][ks] = r * 64 + (((ks * 4 + lq) ^ lb) << 3);
    }

    const int nt = nseg * 32;   // BK=64 -> 32 tiles/segment; nt even, >= 32

    auto stage = [&](int tile, u16* Ad, u16* Bd) {   // 4 global_load_lds / wave
        int sn = tile >> 5;
        size_t kn = (size_t)(tile & 31) << 6;
        const u16* Ap = (sn == 0) ? A0 : ((sn == 1) ? A1 : A2);
        const u16* Bp = (sn == 0) ? B0 : ((sn == 1) ? B1 : B2);
        const u16* gA = Ap + ago + kn;
        const u16* gB = Bp + bgo + kn;
        gload16(gA, Ad + ldsW);
        gload16(gA + (size_t)8 * GN, Ad + ldsW + 512);
        gload16(gB, Bd + ldsW);
        gload16(gB + (size_t)8 * GN, Bd + ldsW + 512);
    };
    auto compute = [&](const u16* Asrc, const u16* Bsrc) {
#pragma unroll
        for (int ks = 0; ks < 2; ++ks) {
            bf16x8 af[4], bq[2];
#pragma unroll
            for (int mi = 0; mi < 4; ++mi)
                af[mi] = *(const bf16x8*)&Asrc[aoff[mi][ks]];
#pragma unroll
            for (int ni = 0; ni < 2; ++ni)
                bq[ni] = *(const bf16x8*)&Bsrc[boff[ni][ks]];
#pragma unroll
            for (int mi = 0; mi < 4; ++mi)
#pragma unroll
                for (int ni = 0; ni < 2; ++ni)
                    acc[mi][ni] = __builtin_amdgcn_mfma_f32_16x16x32_bf16(
                        af[mi], bq[ni], acc[mi][ni], 0, 0, 0);
        }
    };

    // T3+T4 depth-2 pipeline: counted vmcnt, raw barriers, never drain mid-loop.
    stage(0, As0, Bs0);                       // 4 loads in flight
    stage(1, As1, Bs1);                       // 8 in flight
    asm volatile("s_waitcnt vmcnt(4)" ::: "memory");   // buf0 ready
    __builtin_amdgcn_s_barrier();
    for (int tt = 0; tt < nt - 2; tt += 2) {
        compute(As0, Bs0);                    // tile tt
        asm volatile("s_waitcnt lgkmcnt(0)" ::: "memory");
        __builtin_amdgcn_s_barrier();         // all waves done reading buf0
        stage(tt + 2, As0, Bs0);              // overwrite buf0; 8 in flight
        asm volatile("s_waitcnt vmcnt(4)" ::: "memory");  // tile tt+1 ready
        __builtin_amdgcn_s_barrier();
        compute(As1, Bs1);                    // tile tt+1
        asm volatile("s_waitcnt lgkmcnt(0)" ::: "memory");
        __builtin_amdgcn_s_barrier();         // all waves done reading buf1
        stage(tt + 3, As1, Bs1);              // overwrite buf1; 8 in flight
        asm volatile("s_waitcnt vmcnt(4)" ::: "memory");  // tile tt+2 ready
        __builtin_amdgcn_s_barrier();
    }
    compute(As0, Bs0);                        // tile nt-2
    asm volatile("s_waitcnt vmcnt(0)" ::: "memory");     // tile nt-1 ready
    __builtin_amdgcn_s_barrier();
    compute(As1, Bs1);                        // tile nt-1

    // epilogue: C/D frag mapping col = l&15, row = (l>>4)*4 + r
#pragma unroll
    for (int mi = 0; mi < 4; ++mi) {
#pragma unroll
        for (int r = 0; r < 4; ++r) {
            int gm = m0 + wr * 64 + mi * 16 + lq * 4 + r;
            size_t rowo = (size_t)gm * GN;
#pragma unroll
            for (int ni = 0; ni < 2; ++ni) {
                int gn = n0 + wc * 32 + ni * 16 + lrow;
                float v = acc[mi][ni][r];
                if (MODE == 1) v = v + Dm[rowo + gn];
                else if (MODE == 2) v = Dm[rowo + gn] - v;
                else if (MODE == 3) v = ((gm == gn) ? 2.0f : 0.0f) - v;
                if (WF32) Of[rowo + gn] = v;
                if (WHI) {
                    u16 h = f2bf(v);
                    Ohi[rowo + gn] = h;
                    if (WLO) Olo[rowo + gn] = f2bf(v - bf2f(h));
                }
            }
        }
    }
}

// ---------------- host ----------------

extern "C" void kernel_launch(void* const* d_in, const int* in_sizes, int n_in,
                              void* d_out, int out_size, void* d_ws, size_t ws_size,
                              hipStream_t stream)
{
    const int n = GN;
    const float* x  = (const float*)d_in[0];
    const float* y  = (const float*)d_in[1];
    const float* u  = (const float*)d_in[2];
    const float* P  = (const float*)d_in[3];
    const float* Q  = (const float*)d_in[4];
    const float* R  = (const float*)d_in[5];
    const float* A  = (const float*)d_in[6];
    const float* B  = (const float*)d_in[7];
    const float* C  = (const float*)d_in[8];
    const float* D  = (const float*)d_in[9];
    const float* c1 = (const float*)d_in[10];
    const float* c2 = (const float*)d_in[11];

    float* out  = (float*)d_out;
    float* xout = out;          // n
    float* Pf   = out + n;      // n*n fp32: Pk, becomes P_out in place

    // 10 bf16 NxN slots + small fp32 vectors
    u16* wsu = (u16*)d_ws;
    u16* S0 = wsu + 0 * NNE;  // C_hi  -> G_hi
    u16* S1 = wsu + 1 * NNE;  // C_lo  -> G_lo
    u16* S2 = wsu + 2 * NNE;  // Pk_hi -> X odd slots / X5_hi
    u16* S3 = wsu + 3 * NNE;  // Pk_lo -> X5_lo
    u16* S4 = wsu + 4 * NNE;  // T_hi  -> X even slots (X4)
    u16* S5 = wsu + 5 * NNE;  // T_lo
    u16* S6 = wsu + 6 * NNE;  // Py_hi
    u16* S7 = wsu + 7 * NNE;  // Py_lo
    u16* S8 = wsu + 8 * NNE;  // E_hi  -> H_hi
    u16* S9 = wsu + 9 * NNE;  // E_lo  -> H_lo
    float* vecs = (float*)(wsu + 10 * NNE);
    float* t1   = vecs + 0 * n;
    float* xp   = vecs + 1 * n;
    float* ob   = vecs + 2 * n;
    float* ytmp = vecs + 3 * n;
    float* rr   = vecs + 4 * n;
    float* va   = vecs + 5 * n;
    float* vb   = vecs + 6 * n;
    float* z0   = vecs + 7 * n;
    float* z1   = vecs + 8 * n;
    float* rho  = vecs + 9 * n;
    float* scal = vecs + 10 * n;

    dim3 blk256(256), blk512(512);
    dim3 gg(16, 16);

    // Pk = P + Q (fp32 into d_out + hi/lo) ; C -> hi/lo
    fuse_pk<<<4096, blk256, 0, stream>>>(P, Q, Pf, S2, S3);
    conv_hl<<<4096, blk256, 0, stream>>>(C, S0, S1);

    // xp = A x + B u + c1 ; rr = y - (C xp + D u + c2)
    matvec_f32<<<512, blk256, 0, stream>>>(B, u, c1, t1, n);
    matvec_f32<<<512, blk256, 0, stream>>>(A, x, t1, xp, n);
    matvec_f32<<<512, blk256, 0, stream>>>(D, u, c2, ob, n);
    matvec_f32<<<512, blk256, 0, stream>>>(C, xp, ob, ytmp, n);
    vec_sub<<<8, blk256, 0, stream>>>(y, ytmp, rr, n);

    // T = TN(C, Pk) (full split, 3-seg) -> S4/S5
    mfma_gemm<0, 1, 1, 0><<<gg, blk512, 0, stream>>>(S0, S2, S0, S3, S1, S2, 3,
                                                     nullptr, nullptr, S4, S5);
    // Py = TN(T, C) + R (full split, 3-seg) -> S6/S7
    mfma_gemm<1, 1, 1, 0><<<gg, blk512, 0, stream>>>(S4, S0, S4, S1, S5, S0, 3,
                                                     R, nullptr, S6, S7);
    // G = T^T -> S0/S1 (C bf16 dead)
    transpose_pair<<<dim3(64, 64), blk256, 0, stream>>>(S4, S5, S0, S1);

    // power iteration for lambda_max(Py) -> alpha = 2/(1.3*lam)
    vec_fill<<<8, blk256, 0, stream>>>(va, 1.0f, n);
    float* pa = va; float* pb = vb;
    for (int i = 0; i < 9; ++i) {
        matvec_hl<<<512, blk256, 0, stream>>>(S6, nullptr, pa, nullptr, pb, 1.0f, n);
        float* tmp = pa; pa = pb; pb = tmp;
    }
    normsq<<<1, blk256, 0, stream>>>(pa, scal + 0, n);
    matvec_hl<<<512, blk256, 0, stream>>>(S6, nullptr, pa, nullptr, pb, 1.0f, n);
    normsq<<<1, blk256, 0, stream>>>(pb, scal + 1, n);
    alpha_k<<<1, 1, 0, stream>>>(scal + 0, scal + 1, scal + 2);

    // X1 = alpha*(2I - alpha*Py), elementwise (free first NS step) -> S2
    ns_init<<<4096, blk256, 0, stream>>>(S6, S7, scal + 2, S2);

    // 3 cheap NS iterations (hi-only): S2 -> S4 -> S2 -> S4
    u16* ch = S2; u16* oh = S4;
    for (int it = 0; it < 3; ++it) {
        mfma_gemm<3, 1, 0, 0><<<gg, blk512, 0, stream>>>(ch, S6, nullptr, nullptr, nullptr, nullptr, 1,
                                                         nullptr, nullptr, S8, nullptr); // E = 2I - X Py
        mfma_gemm<0, 1, 0, 0><<<gg, blk512, 0, stream>>>(S8, ch, nullptr, nullptr, nullptr, nullptr, 1,
                                                         nullptr, nullptr, oh, nullptr); // Xn = E X
        u16* tmp = ch; ch = oh; oh = tmp;
    }
    // exact-split NS iteration from X4 (== S4, hi-only): X5 -> S2/S3
    mfma_gemm<3, 1, 1, 0><<<gg, blk512, 0, stream>>>(S4, S6, S4, S7, nullptr, nullptr, 2,
                                                     nullptr, nullptr, S8, S9);          // E = 2I - X4*Py(full)
    mfma_gemm<0, 1, 1, 0><<<gg, blk512, 0, stream>>>(S8, S4, S9, S4, nullptr, nullptr, 2,
                                                     nullptr, nullptr, S2, S3);          // X5 = E(full)*X4

    // H = TN(G, X5) (2-seg: Gh*Xh + Gh*Xl) -> S8/S9
    mfma_gemm<0, 1, 1, 0><<<gg, blk512, 0, stream>>>(S0, S2, S0, S3, nullptr, nullptr, 2,
                                                     nullptr, nullptr, S8, S9);
    // P_out = Pk - TN(H, G) (2-seg: Hh*Gh + Hl*Gh) -> Pf in place
    mfma_gemm<2, 0, 0, 1><<<gg, blk512, 0, stream>>>(S8, S0, S9, S0, nullptr, nullptr, 2,
                                                     Pf, Pf, nullptr, nullptr);

    // z = Py^{-1} rr by X-preconditioned iterative refinement (2 steps)
    matvec_hl<<<512, blk256, 0, stream>>>(S2, S3, rr, nullptr, z0, 1.0f, n);   // z0 = X r
    matvec_hl<<<512, blk256, 0, stream>>>(S6, S7, z0, rr, rho, -1.0f, n);      // rho = r - Py z0
    matvec_hl<<<512, blk256, 0, stream>>>(S2, S3, rho, z0, z1, 1.0f, n);       // z1 = z0 + X rho
    matvec_hl<<<512, blk256, 0, stream>>>(S6, S7, z1, rr, rho, -1.0f, n);      // rho = r - Py z1
    matvec_hl<<<512, blk256, 0, stream>>>(S2, S3, rho, z1, z0, 1.0f, n);       // z2 = z1 + X rho
    // x_out = xp + G z2
    matvec_hl<<<512, blk256, 0, stream>>>(S0, S1, z0, xp, xout, 1.0f, n);
}

// Round 6
// 425.505 us; speedup vs baseline: 2.8974x; 2.3386x over previous
//
#include <hip/hip_runtime.h>
#include <math.h>

// ---------------------------------------------------------------------------
// UKF(2048) == linear Kalman update (affine model => sigma machinery collapses).
// With C = I + D (||D||~0.02):
//   xp = A x + B u + c1 ; Pk = P + Q (fp32 Pf)
//   T  = Pk + D Pk                (1 hi-only MFMA unit, fp32 base)
//   Py = T + T D^T + R            (1 hi-only MFMA unit, fp32 base)
//   G  = T^T
//   X ~= Py^{-1}, hi-only Newton-Schulz: X1 = a(2I - a Py) analytic,
//        then 3 iterations (E = 2I - X Py ; X <- E X), bf16-floor residual
//   H = G X (2 units) ; P_out = Pk - H G^T (2 units)
//   z = Py^{-1} r via X-preconditioned refinement (matvecs) ; x_out = xp + G z
// GEMM: TN MFMA ( TN(A,B)[m][n] = sum_k A[m][k]*B[n][k] ), 128x128 tile,
// 8 waves, BK=64, XOR-swizzled LDS (pre-swizzled global source), DEPTH-4
// prefetch: 4 LDS buffers (128 KB), counted s_waitcnt vmcnt(12) + raw
// s_barrier -> each tile's loads get ~3 tile-periods to land (grid = 256
// blocks = 1 block/CU, so latency must be hidden inside the block).
// ---------------------------------------------------------------------------

typedef unsigned short u16;
typedef unsigned int u32;
typedef __attribute__((ext_vector_type(8))) short bf16x8;
typedef __attribute__((ext_vector_type(4))) float f32x4;

#define GN 2048
#define NNE ((size_t)GN * (size_t)GN)

#define WAITVM(N) asm volatile("s_waitcnt vmcnt(" #N ")" ::: "memory")
#define WAITLG()  asm volatile("s_waitcnt lgkmcnt(0)" ::: "memory")

__device__ __forceinline__ u16 f2bf(float f) {
    union { float f; u32 u; } x; x.f = f;
    u32 r = x.u + 0x7fffu + ((x.u >> 16) & 1u);   // RNE
    return (u16)(r >> 16);
}
__device__ __forceinline__ float bf2f(u16 b) {
    union { u32 u; float f; } x; x.u = ((u32)b) << 16;
    return x.f;
}

__device__ __forceinline__ void gload16(const u16* g, u16* l) {
    __builtin_amdgcn_global_load_lds((const __attribute__((address_space(1))) u32*)g,
                                     (__attribute__((address_space(3))) u32*)l, 16, 0, 0);
}

// ---------------- elementwise / conversion ----------------

// Pf = P + Q (fp32), Pkh = bf16 hi of Pf
__global__ void fuse_pk(const float* __restrict__ P, const float* __restrict__ Q,
                        float* __restrict__ Pf, u16* __restrict__ Ph)
{
    size_t i = (size_t)blockIdx.x * 256 + threadIdx.x;   // over NNE/4
    float4 p = ((const float4*)P)[i];
    float4 q = ((const float4*)Q)[i];
    float s[4] = {p.x + q.x, p.y + q.y, p.z + q.z, p.w + q.w};
    ((float4*)Pf)[i] = make_float4(s[0], s[1], s[2], s[3]);
    ushort4 h;
    u16* hp = (u16*)&h;
#pragma unroll
    for (int e = 0; e < 4; ++e) hp[e] = f2bf(s[e]);
    ((ushort4*)Ph)[i] = h;
}

// Dh = bf16(C - I)
__global__ void conv_delta(const float* __restrict__ C, u16* __restrict__ Dh)
{
    size_t i = (size_t)blockIdx.x * 256 + threadIdx.x;   // over NNE/4
    size_t base = i * 4;
    u32 row = (u32)(base >> 11);
    u32 col0 = (u32)(base & (GN - 1));
    float4 p = ((const float4*)C)[i];
    float s[4] = {p.x, p.y, p.z, p.w};
    ushort4 h;
    u16* hp = (u16*)&h;
#pragma unroll
    for (int e = 0; e < 4; ++e)
        hp[e] = f2bf(s[e] - ((row == col0 + e) ? 1.0f : 0.0f));
    ((ushort4*)Dh)[i] = h;
}

__global__ void transpose_pair(const u16* __restrict__ Sh, const u16* __restrict__ Sl,
                               u16* __restrict__ Dh, u16* __restrict__ Dl)
{
    __shared__ u16 th[32][33];
    __shared__ u16 tl[32][33];
    int bi = blockIdx.y * 32, bj = blockIdx.x * 32;
    int r = threadIdx.x >> 5, c = threadIdx.x & 31;
    for (int rr = r; rr < 32; rr += 8) {
        th[rr][c] = Sh[(size_t)(bi + rr) * GN + bj + c];
        tl[rr][c] = Sl[(size_t)(bi + rr) * GN + bj + c];
    }
    __syncthreads();
    for (int rr = r; rr < 32; rr += 8) {
        Dh[(size_t)(bj + rr) * GN + bi + c] = th[c][rr];
        Dl[(size_t)(bj + rr) * GN + bi + c] = tl[c][rr];
    }
}

// X1 = a*(2I - a*Py) : first Newton-Schulz step is elementwise for X0 = a*I
__global__ void ns_init(const u16* __restrict__ Pyh, const u16* __restrict__ Pyl,
                        const float* __restrict__ alphap, u16* __restrict__ X)
{
    float a = alphap[0];
    size_t i4 = (size_t)blockIdx.x * 256 + threadIdx.x;   // over NNE/4
    size_t base = i4 * 4;
    u32 row = (u32)(base >> 11);
    u32 col0 = (u32)(base & (GN - 1));
    ushort4 h = ((const ushort4*)Pyh)[i4];
    ushort4 lo = ((const ushort4*)Pyl)[i4];
    u16 hv[4] = {h.x, h.y, h.z, h.w};
    u16 lv[4] = {lo.x, lo.y, lo.z, lo.w};
    ushort4 o;
    u16* op = (u16*)&o;
#pragma unroll
    for (int e = 0; e < 4; ++e) {
        float py = bf2f(hv[e]) + bf2f(lv[e]);
        float v = a * (((row == col0 + e) ? 2.0f : 0.0f) - a * py);
        op[e] = f2bf(v);
    }
    ((ushort4*)X)[i4] = o;
}

// ---------------- vector kernels ----------------

// out[row] = addv[row] + sign*( dot(A[row,:],v1) + dot(B[row,:],v2) )
__global__ void matvec_dual_f32(const float* __restrict__ A, const float* __restrict__ v1,
                                const float* __restrict__ B, const float* __restrict__ v2,
                                const float* __restrict__ addv, float* __restrict__ out,
                                float sign, int n)
{
    int wid = threadIdx.x >> 6, lane = threadIdx.x & 63;
    int row = blockIdx.x * 4 + wid;
    if (row >= n) return;
    const float* ar = A + (size_t)row * n;
    const float* br = B + (size_t)row * n;
    float s = 0.f;
    for (int j = lane; j < n; j += 64) s += ar[j] * v1[j] + br[j] * v2[j];
#pragma unroll
    for (int off = 32; off > 0; off >>= 1) s += __shfl_down(s, off);
    if (lane == 0) out[row] = addv[row] + sign * s;
}

// out[row] = (addv ? addv[row] : 0) + sign * dot((hi+lo)[row,:], v)
__global__ void matvec_hl(const u16* __restrict__ Mh, const u16* __restrict__ Ml,
                          const float* __restrict__ v, const float* __restrict__ addv,
                          float* __restrict__ out, float sign, int n)
{
    int wid = threadIdx.x >> 6, lane = threadIdx.x & 63;
    int row = blockIdx.x * 4 + wid;
    if (row >= n) return;
    const u16* hr = Mh + (size_t)row * n;
    const u16* lr = Ml ? Ml + (size_t)row * n : (const u16*)0;
    float s = 0.f;
    for (int j = lane * 8; j < n; j += 512) {
        uint4 hb = *(const uint4*)&hr[j];
        float4 v0 = *(const float4*)&v[j];
        float4 v1 = *(const float4*)&v[j + 4];
        u32 hw[4] = {hb.x, hb.y, hb.z, hb.w};
        float m[8];
#pragma unroll
        for (int e = 0; e < 4; ++e) {
            m[2 * e]     = bf2f((u16)(hw[e] & 0xffffu));
            m[2 * e + 1] = bf2f((u16)(hw[e] >> 16));
        }
        if (lr) {
            uint4 lb = *(const uint4*)&lr[j];
            u32 lw[4] = {lb.x, lb.y, lb.z, lb.w};
#pragma unroll
            for (int e = 0; e < 4; ++e) {
                m[2 * e]     += bf2f((u16)(lw[e] & 0xffffu));
                m[2 * e + 1] += bf2f((u16)(lw[e] >> 16));
            }
        }
        s += m[0] * v0.x + m[1] * v0.y + m[2] * v0.z + m[3] * v0.w
           + m[4] * v1.x + m[5] * v1.y + m[6] * v1.z + m[7] * v1.w;
    }
#pragma unroll
    for (int off = 32; off > 0; off >>= 1) s += __shfl_down(s, off);
    if (lane == 0) out[row] = (addv ? addv[row] : 0.f) + sign * s;
}

__global__ void vec_sub(const float* __restrict__ a, const float* __restrict__ b,
                        float* __restrict__ o, int n)
{
    int i = blockIdx.x * 256 + threadIdx.x;
    if (i < n) o[i] = a[i] - b[i];
}

__global__ void vec_fill(float* __restrict__ o, float val, int n)
{
    int i = blockIdx.x * 256 + threadIdx.x;
    if (i < n) o[i] = val;
}

__global__ void normsq(const float* __restrict__ v, float* __restrict__ out, int n)
{
    __shared__ float sm[256];
    float s = 0.f;
    for (int i = threadIdx.x; i < n; i += 256) { float x = v[i]; s += x * x; }
    sm[threadIdx.x] = s;
    __syncthreads();
    for (int w = 128; w > 0; w >>= 1) {
        if (threadIdx.x < w) sm[threadIdx.x] += sm[threadIdx.x + w];
        __syncthreads();
    }
    if (threadIdx.x == 0) out[0] = sm[0];
}

__global__ void alpha_k(const float* __restrict__ ns9, const float* __restrict__ ns10,
                        float* __restrict__ alpha)
{
    float lam = sqrtf(ns10[0] / ns9[0]);
    alpha[0] = 2.0f / (1.3f * lam);
}

// ---------- MFMA TN-GEMM: 128x128, 8 waves, BK=64, DEPTH-4 prefetch --------
// O = op(MODE){ sum_s A_s B_s^T } ; MODE 0:S 1:S+Dm 2:Dm-S 3:2I-S 4:S+Dm+Dm2
template <int MODE, int WHI, int WLO, int WF32>
__global__ __launch_bounds__(512, 2) void mfma_gemm(
    const u16* A0, const u16* B0, const u16* A1, const u16* B1, int nseg,
    const float* Dm, const float* Dm2, float* Of, u16* Ohi, u16* Olo)
{
    __shared__ __align__(16) u16 As0[128 * 64];
    __shared__ __align__(16) u16 Bs0[128 * 64];
    __shared__ __align__(16) u16 As1[128 * 64];
    __shared__ __align__(16) u16 Bs1[128 * 64];
    __shared__ __align__(16) u16 As2[128 * 64];
    __shared__ __align__(16) u16 Bs2[128 * 64];
    __shared__ __align__(16) u16 As3[128 * 64];
    __shared__ __align__(16) u16 Bs3[128 * 64];
    const int t = threadIdx.x;
    const int wid = t >> 6, l = t & 63;
    const int wr = wid >> 2, wc = wid & 3;            // 2x4 waves, tile 64x32
    const int m0 = blockIdx.y * 128, n0 = blockIdx.x * 128;

    f32x4 acc[4][2] = {};

    // staging: wave w rows [w*16, w*16+16), 2 gloads of 8 rows per operand.
    // LDS linear; swizzle via permuted GLOBAL source column (rule #21):
    // phys slot content(row, sl) = global col sl^(row&7); row&7 == l>>3.
    const int srow = l >> 3;                            // 0..7
    const int scol = (((l & 7) ^ srow) << 3);           // source col (elems)
    const size_t ago = (size_t)(m0 + wid * 16 + srow) * GN + scol;
    const size_t bgo = (size_t)(n0 + wid * 16 + srow) * GN + scol;
    const int ldsW = wid * 1024;

    // read side: logical k-slot (ks*4 + l>>4) XOR (row&7)
    const int lrow = l & 15;
    const int lq = l >> 4;
    const int lb = l & 7;
    int aoff[4][2], boff[2][2];
#pragma unroll
    for (int mi = 0; mi < 4; ++mi) {
        int r = wr * 64 + mi * 16 + lrow;
#pragma unroll
        for (int ks = 0; ks < 2; ++ks)
            aoff[mi][ks] = r * 64 + (((ks * 4 + lq) ^ lb) << 3);
    }
#pragma unroll
    for (int ni = 0; ni < 2; ++ni) {
        int r = wc * 32 + ni * 16 + lrow;
#pragma unroll
        for (int ks = 0; ks < 2; ++ks)
            boff[ni][ks] = r * 64 + (((ks * 4 + lq) ^ lb) << 3);
    }

    const int nt = nseg * 32;   // BK=64 -> 32 tiles/segment; nt in {32,64}

    auto stage = [&](int tile, u16* Ad, u16* Bd) {   // 4 global_load_lds / wave
        int sn = tile >> 5;
        size_t kn = (size_t)(tile & 31) << 6;
        const u16* Ap = (sn == 0) ? A0 : A1;
        const u16* Bp = (sn == 0) ? B0 : B1;
        const u16* gA = Ap + ago + kn;
        const u16* gB = Bp + bgo + kn;
        gload16(gA, Ad + ldsW);
        gload16(gA + (size_t)8 * GN, Ad + ldsW + 512);
        gload16(gB, Bd + ldsW);
        gload16(gB + (size_t)8 * GN, Bd + ldsW + 512);
    };
    auto compute = [&](const u16* Asrc, const u16* Bsrc) {
        __builtin_amdgcn_s_setprio(1);
#pragma unroll
        for (int ks = 0; ks < 2; ++ks) {
            bf16x8 af[4], bq[2];
#pragma unroll
            for (int mi = 0; mi < 4; ++mi)
                af[mi] = *(const bf16x8*)&Asrc[aoff[mi][ks]];
#pragma unroll
            for (int ni = 0; ni < 2; ++ni)
                bq[ni] = *(const bf16x8*)&Bsrc[boff[ni][ks]];
#pragma unroll
            for (int mi = 0; mi < 4; ++mi)
#pragma unroll
                for (int ni = 0; ni < 2; ++ni)
                    acc[mi][ni] = __builtin_amdgcn_mfma_f32_16x16x32_bf16(
                        af[mi], bq[ni], acc[mi][ni], 0, 0, 0);
        }
        __builtin_amdgcn_s_setprio(0);
    };

    // ---- depth-4 pipeline: each tile's loads get ~3 tile-periods to land ---
    stage(0, As0, Bs0);
    stage(1, As1, Bs1);
    stage(2, As2, Bs2);
    stage(3, As3, Bs3);                     // 16 loads in flight
    int u = 0;
    for (; u + 8 <= nt; u += 4) {
        WAITVM(12); __builtin_amdgcn_s_barrier();
        compute(As0, Bs0);                  // tile u
        WAITLG(); __builtin_amdgcn_s_barrier();
        stage(u + 4, As0, Bs0);
        WAITVM(12); __builtin_amdgcn_s_barrier();
        compute(As1, Bs1);                  // tile u+1
        WAITLG(); __builtin_amdgcn_s_barrier();
        stage(u + 5, As1, Bs1);
        WAITVM(12); __builtin_amdgcn_s_barrier();
        compute(As2, Bs2);                  // tile u+2
        WAITLG(); __builtin_amdgcn_s_barrier();
        stage(u + 6, As2, Bs2);
        WAITVM(12); __builtin_amdgcn_s_barrier();
        compute(As3, Bs3);                  // tile u+3
        WAITLG(); __builtin_amdgcn_s_barrier();
        stage(u + 7, As3, Bs3);
    }
    // tail: u == nt-4, no more stages, counted drain 12/8/4/0
    WAITVM(12); __builtin_amdgcn_s_barrier();
    compute(As0, Bs0);
    WAITVM(8);  __builtin_amdgcn_s_barrier();
    compute(As1, Bs1);
    WAITVM(4);  __builtin_amdgcn_s_barrier();
    compute(As2, Bs2);
    WAITVM(0);  __builtin_amdgcn_s_barrier();
    compute(As3, Bs3);

    // epilogue: C/D frag mapping col = l&15, row = (l>>4)*4 + r
#pragma unroll
    for (int mi = 0; mi < 4; ++mi) {
#pragma unroll
        for (int r = 0; r < 4; ++r) {
            int gm = m0 + wr * 64 + mi * 16 + lq * 4 + r;
            size_t rowo = (size_t)gm * GN;
#pragma unroll
            for (int ni = 0; ni < 2; ++ni) {
                int gn = n0 + wc * 32 + ni * 16 + lrow;
                float v = acc[mi][ni][r];
                if (MODE == 1) v = v + Dm[rowo + gn];
                else if (MODE == 2) v = Dm[rowo + gn] - v;
                else if (MODE == 3) v = ((gm == gn) ? 2.0f : 0.0f) - v;
                else if (MODE == 4) v = v + Dm[rowo + gn] + Dm2[rowo + gn];
                if (WF32) Of[rowo + gn] = v;
                if (WHI) {
                    u16 h = f2bf(v);
                    Ohi[rowo + gn] = h;
                    if (WLO) Olo[rowo + gn] = f2bf(v - bf2f(h));
                }
            }
        }
    }
}

// ---------------- host ----------------

extern "C" void kernel_launch(void* const* d_in, const int* in_sizes, int n_in,
                              void* d_out, int out_size, void* d_ws, size_t ws_size,
                              hipStream_t stream)
{
    const int n = GN;
    const float* x  = (const float*)d_in[0];
    const float* y  = (const float*)d_in[1];
    const float* u  = (const float*)d_in[2];
    const float* P  = (const float*)d_in[3];
    const float* Q  = (const float*)d_in[4];
    const float* R  = (const float*)d_in[5];
    const float* A  = (const float*)d_in[6];
    const float* B  = (const float*)d_in[7];
    const float* C  = (const float*)d_in[8];
    const float* D  = (const float*)d_in[9];
    const float* c1 = (const float*)d_in[10];
    const float* c2 = (const float*)d_in[11];

    float* out  = (float*)d_out;
    float* xout = out;          // n
    float* Pf   = out + n;      // n*n fp32: Pk, becomes P_out in place

    // 8 bf16 NxN slots + Tf fp32 (2 slots) + small fp32 vectors  (~84 MB)
    u16* wsu = (u16*)d_ws;
    u16* S0 = wsu + 0 * NNE;  // Delta_h -> E_h
    u16* S1 = wsu + 1 * NNE;  // Pk_h    -> X (odd)  [final X]
    u16* S2 = wsu + 2 * NNE;  // T_h     -> X (even) -> H_l
    u16* S3 = wsu + 3 * NNE;  // T_l     -> H_h
    u16* S4 = wsu + 4 * NNE;  // G_h
    u16* S5 = wsu + 5 * NNE;  // G_l
    u16* S6 = wsu + 6 * NNE;  // Py_h
    u16* S7 = wsu + 7 * NNE;  // Py_l
    float* Tf = (float*)(wsu + 8 * NNE);   // fp32 T (slots 8-9)
    float* vecs = (float*)(wsu + 10 * NNE);
    float* w2   = vecs + 0 * n;
    float* xp   = vecs + 1 * n;
    float* rr   = vecs + 2 * n;
    float* va   = vecs + 3 * n;
    float* vb   = vecs + 4 * n;
    float* z0   = vecs + 5 * n;
    float* z1   = vecs + 6 * n;
    float* rho  = vecs + 7 * n;
    float* scal = vecs + 8 * n;

    dim3 blk256(256), blk512(512);
    dim3 gg(16, 16);

    // Pf = P + Q (+ bf16 hi) ; Delta = C - I (bf16 hi)
    fuse_pk<<<4096, blk256, 0, stream>>>(P, Q, Pf, S1);
    conv_delta<<<4096, blk256, 0, stream>>>(C, S0);

    // xp = A x + B u + c1 ; rr = (y - c2) - (C xp + D u)
    matvec_dual_f32<<<512, blk256, 0, stream>>>(A, x, B, u, c1, xp, 1.0f, n);
    vec_sub<<<8, blk256, 0, stream>>>(y, c2, w2, n);
    matvec_dual_f32<<<512, blk256, 0, stream>>>(C, xp, D, u, w2, rr, -1.0f, n);

    // T = Pk + TN(Delta_h, Pk_h)  -> Tf (fp32) + Th(S2)/Tl(S3)
    mfma_gemm<1, 1, 1, 1><<<gg, blk512, 0, stream>>>(S0, S1, nullptr, nullptr, 1,
                                                     Pf, nullptr, Tf, S2, S3);
    // Py = Tf + R + TN(T_h, Delta_h) -> Py_h(S6)/Py_l(S7)
    mfma_gemm<4, 1, 1, 0><<<gg, blk512, 0, stream>>>(S2, S0, nullptr, nullptr, 1,
                                                     Tf, R, nullptr, S6, S7);
    // G = T^T -> S4/S5
    transpose_pair<<<dim3(64, 64), blk256, 0, stream>>>(S2, S3, S4, S5);

    // power iteration for lambda_max(Py) -> alpha = 2/(1.3*lam)
    vec_fill<<<8, blk256, 0, stream>>>(va, 1.0f, n);
    float* pa = va; float* pb = vb;
    for (int i = 0; i < 7; ++i) {
        matvec_hl<<<512, blk256, 0, stream>>>(S6, nullptr, pa, nullptr, pb, 1.0f, n);
        float* tmp = pa; pa = pb; pb = tmp;
    }
    normsq<<<1, blk256, 0, stream>>>(pa, scal + 0, n);
    matvec_hl<<<512, blk256, 0, stream>>>(S6, nullptr, pa, nullptr, pb, 1.0f, n);
    normsq<<<1, blk256, 0, stream>>>(pb, scal + 1, n);
    alpha_k<<<1, 1, 0, stream>>>(scal + 0, scal + 1, scal + 2);

    // X1 = alpha*(2I - alpha*Py), elementwise -> S2 (T_h dead after G/Py)
    ns_init<<<4096, blk256, 0, stream>>>(S6, S7, scal + 2, S2);

    // 3 cheap NS iterations (hi-only): X: S2 -> S1 -> S2 -> S1
    u16* ch = S2; u16* oh = S1;
    for (int it = 0; it < 3; ++it) {
        mfma_gemm<3, 1, 0, 0><<<gg, blk512, 0, stream>>>(ch, S6, nullptr, nullptr, 1,
                                                         nullptr, nullptr, nullptr, S0, nullptr); // E = 2I - X Py
        mfma_gemm<0, 1, 0, 0><<<gg, blk512, 0, stream>>>(S0, ch, nullptr, nullptr, 1,
                                                         nullptr, nullptr, nullptr, oh, nullptr); // Xn = E X
        u16* tmp = ch; ch = oh; oh = tmp;
    }
    // final X = S1 (hi-only)

    // H = TN(G_h, X) + TN(G_l, X) -> H_h(S3)/H_l(S2)
    mfma_gemm<0, 1, 1, 0><<<gg, blk512, 0, stream>>>(S4, S1, S5, S1, 2,
                                                     nullptr, nullptr, nullptr, S3, S2);
    // P_out = Pf - [TN(H_h, G_h) + TN(H_l, G_h)] -> Pf in place
    mfma_gemm<2, 0, 0, 1><<<gg, blk512, 0, stream>>>(S3, S4, S2, S4, 2,
                                                     Pf, nullptr, Pf, nullptr, nullptr);

    // z = Py^{-1} rr by X-preconditioned iterative refinement (3 steps)
    matvec_hl<<<512, blk256, 0, stream>>>(S1, nullptr, rr, nullptr, z0, 1.0f, n);  // z0 = X r
    matvec_hl<<<512, blk256, 0, stream>>>(S6, S7, z0, rr, rho, -1.0f, n);          // rho = r - Py z0
    matvec_hl<<<512, blk256, 0, stream>>>(S1, nullptr, rho, z0, z1, 1.0f, n);      // z1 = z0 + X rho
    matvec_hl<<<512, blk256, 0, stream>>>(S6, S7, z1, rr, rho, -1.0f, n);          // rho = r - Py z1
    matvec_hl<<<512, blk256, 0, stream>>>(S1, nullptr, rho, z1, z0, 1.0f, n);      // z2 = z1 + X rho
    matvec_hl<<<512, blk256, 0, stream>>>(S6, S7, z0, rr, rho, -1.0f, n);          // rho = r - Py z2
    matvec_hl<<<512, blk256, 0, stream>>>(S1, nullptr, rho, z0, z1, 1.0f, n);      // z3 = z2 + X rho
    // x_out = xp + G z3
    matvec_hl<<<512, blk256, 0, stream>>>(S4, S5, z1, xp, xout, 1.0f, n);
}